// Round 4
// baseline (220.408 us; speedup 1.0000x reference)
//
#include <hip/hip_runtime.h>

#define ETA_MIN 2.302585092994046f  // log(10)
#define ETA_MAX 20.0f

typedef float v4f __attribute__((ext_vector_type(4)));

// Elementwise: w_i = (loss_i > eta) ? 0 : 1 - loss_i/eta,
// eta = clamp(eta_value[0], ETA_MIN, ETA_MAX).
// Memory-bound: 256 MB total traffic, roofline ~41 us at 6.3 TB/s (m13 copy).
//
// EMPIRICAL LOG:
//  r0/r3 (this structure + nt load/store): 218.6 / 218.9 us total
//         (~160 us harness fills + ~58 us kernel = 4.5 TB/s). Noise +-2 us.
//  r1 (UNROLL=4, 8MB-strided): +7.8 us  — per-wave MLP regressed.
//  r2 (UNROLL=8, contiguous 32KB/block): +24.8 us — worse still.
//  => one-load-one-store short-lived waves is the best structure so far;
//     CU-level MLP (32 waves x 1 load) beats wave-level batching here.
//
// r4 single-variable change: REMOVE the nontemporal modifiers.
// nt was adopted on theory, never A/B'd. Counter-theory: nt bypasses L2
// allocation, so lane requests ride raw HBM latency and TCC loses burst
// merge/scheduling; the 6.7 TB/s fills and the 6.29 TB/s m13 copy both go
// through L2. One-touch streams lose nothing to allocation (no reuse to
// protect). Plain loads/stores, everything else byte-identical to r0.
__global__ void Weightfun_78374563217418_kernel(const v4f* __restrict__ loss,
                                                const float* __restrict__ eta_ptr,
                                                v4f* __restrict__ out,
                                                int n4) {
    int i = blockIdx.x * blockDim.x + threadIdx.x;
    // uniform scalar broadcast load; clamped per reference
    float eta = eta_ptr[0];
    eta = fminf(fmaxf(eta, ETA_MIN), ETA_MAX);
    float inv_eta = 1.0f / eta;  // one precise divide per thread

    if (i < n4) {
        v4f l = loss[i];
        v4f w;
        w.x = (l.x > eta) ? 0.0f : fmaf(-l.x, inv_eta, 1.0f);
        w.y = (l.y > eta) ? 0.0f : fmaf(-l.y, inv_eta, 1.0f);
        w.z = (l.z > eta) ? 0.0f : fmaf(-l.z, inv_eta, 1.0f);
        w.w = (l.w > eta) ? 0.0f : fmaf(-l.w, inv_eta, 1.0f);
        out[i] = w;
    }
}

extern "C" void kernel_launch(void* const* d_in, const int* in_sizes, int n_in,
                              void* d_out, int out_size, void* d_ws, size_t ws_size,
                              hipStream_t stream) {
    const v4f*   loss = (const v4f*)d_in[0];
    const float* eta  = (const float*)d_in[1];
    v4f*         out  = (v4f*)d_out;

    int n  = in_sizes[0];          // 33554432 = 2^25, divisible by 4
    int n4 = n / 4;                // 8388608
    int block = 256;
    int grid  = (n4 + block - 1) / block;  // 32768 — saturates 256 CUs

    Weightfun_78374563217418_kernel<<<grid, block, 0, stream>>>(loss, eta, out, n4);
}